// Round 8
// baseline (452.144 us; speedup 1.0000x reference)
//
#include <hip/hip_runtime.h>
#include <hip/hip_fp16.h>
#include <cmath>

#define HS 32768
#define NL 16
#define WPL 16   // workgroup slices per level -> 16*16 = 256 WGs, 1/CU
#define TPB 1024

typedef float fvec4 __attribute__((ext_vector_type(4)));

struct ResArr { int r[16]; };

// ---------------- Kernel A': one level per WG, table staged ONCE, free-running loop.
// LDS-bound at the random-gather conflict floor (~141 us: 8M wave-instr x 5.8cyc
// + 4.05e7 conflict cyc / 256 CU). VALU (~68 us incl. inlined normalize) is hidden.
// Round-8: normalize inlined (exact reference ops: add, true divide, clamp) --
// kernel P deleted; its ~50 VALU/point-level ride free under the LDS wall.
// ws[L][N] u32 (fp16x2-packed A,B): 64 lanes x 4 B = 256 B/instr, write amp 1.0.
__global__ __launch_bounds__(TPB, 1) void hash4d_level_kernel(
    const float* __restrict__ coords,
    const float* __restrict__ tstamps,
    const float* __restrict__ tables,
    unsigned* __restrict__ ws,
    int npts, ResArr res)
{
    __shared__ unsigned lds_tab[HS];   // 128 KB: two fp16 feats packed per entry

    const int level = blockIdx.x & 15;
    const int slice = blockIdx.x >> 4;
    const int tid   = (int)threadIdx.x;

    const unsigned P1 = 2654435761u, P2 = 805459861u, P3 = 3674653429u;
    const unsigned MASK4 = (HS - 1u) << 2;   // hash mask pre-shifted to byte offset

    {   // stage table: fvec4 loads (2 entries), pack fp16x2 (RNE), b64 writes
        const fvec4* gt = (const fvec4*)(tables + (size_t)level * HS * 2);
        #pragma unroll 4
        for (int j = tid; j < HS / 2; j += TPB) {
            fvec4 v = gt[j];
            __half2 h0 = __floats2half2_rn(v.x, v.y);
            __half2 h1 = __floats2half2_rn(v.z, v.w);
            uint2 pk;
            pk.x = *(unsigned*)&h0;
            pk.y = *(unsigned*)&h1;
            *(uint2*)&lds_tab[2 * j] = pk;
        }
    }
    __syncthreads();   // the ONLY barrier in this kernel

    const float rf = (float)res.r[level];
    unsigned* wsl = ws + (size_t)level * npts;

    const int per   = (npts + WPL - 1) / WPL;
    const int start = slice * per;
    const int end   = min(start + per, npts);

    for (int i = start + tid; i < end; i += TPB) {
        // inline normalize -- exact reference arithmetic (add, true divide, clamp).
        // 768 B/wave contiguous coords reads; 32 MB working set stays L3-hot.
        float x = coords[3 * i + 0];
        float y = coords[3 * i + 1];
        float z = coords[3 * i + 2];
        float t = tstamps[i];
        t = fminf(fmaxf(t, 0.0f), 1.0f);
        float c0 = (x + 50.0f) / 100.0f;
        float c1 = (y + 50.0f) / 100.0f;
        float c2 = (z + 50.0f) / 100.0f;
        float c3 = t;

        float s0 = c0 * rf, s1 = c1 * rf, s2 = c2 * rf, s3 = c3 * rf;
        float g0 = floorf(s0), g1 = floorf(s1), g2 = floorf(s2), g3 = floorf(s3);
        float f0 = s0 - g0, f1 = s1 - g1, f2 = s2 - g2, f3 = s3 - g3;

        // primes pre-shifted <<2: (x*P)<<2 == x*(P<<2) mod 2^32
        unsigned a0 = ((unsigned)(int)g0) << 2;
        unsigned a1 = (unsigned)(int)g1 * (P1 << 2);
        unsigned a2 = (unsigned)(int)g2 * (P2 << 2);
        unsigned a3 = (unsigned)(int)g3 * (P3 << 2);
        unsigned b0 = a0 + 4u;
        unsigned b1 = a1 + (P1 << 2);
        unsigned b2 = a2 + (P2 << 2);
        unsigned b3 = a3 + (P3 << 2);

        // pre-masked XOR pairs: per-corner address is a single v_xor
        unsigned lo01m[4] = { (a0 ^ a1) & MASK4, (b0 ^ a1) & MASK4,
                              (a0 ^ b1) & MASK4, (b0 ^ b1) & MASK4 };
        unsigned hi23m[4] = { (a2 ^ a3) & MASK4, (b2 ^ a3) & MASK4,
                              (a2 ^ b3) & MASK4, (b2 ^ b3) & MASK4 };

        float m0 = 1.0f - f0, m1 = 1.0f - f1, m2 = 1.0f - f2, m3 = 1.0f - f3;
        float w01_0 = m0 * m1, w01_1 = f0 * m1, w01_2 = m0 * f1, w01_3 = f0 * f1;
        float w23_0 = m2 * m3, w23_1 = f2 * m3, w23_2 = m2 * f3, w23_3 = f2 * f3;

        float A = 0.0f, B = 0.0f;
        #pragma unroll
        for (int hi = 0; hi < 4; ++hi) {
            float whi = (hi == 0) ? w23_0 : (hi == 1) ? w23_1 : (hi == 2) ? w23_2 : w23_3;
            float ax = 0.0f, ay = 0.0f;
            #pragma unroll
            for (int lo = 0; lo < 4; ++lo) {
                unsigned off = hi23m[hi] ^ lo01m[lo];
                float wlo = (lo == 0) ? w01_0 : (lo == 1) ? w01_1 : (lo == 2) ? w01_2 : w01_3;
                unsigned pk = *(const unsigned*)((const char*)lds_tab + off);
                // fused fp16->fp32 convert + fma: no unpack ops.
                asm("v_fma_mix_f32 %0, %1, %2, %0 op_sel:[0,0,0] op_sel_hi:[0,1,0]"
                    : "+v"(ax) : "v"(wlo), "v"(pk));
                asm("v_fma_mix_f32 %0, %1, %2, %0 op_sel:[0,1,0] op_sel_hi:[0,1,0]"
                    : "+v"(ay) : "v"(wlo), "v"(pk));
            }
            A = fmaf(whi, ax, A);
            B = fmaf(whi, ay, B);
        }
        __half2 h = __floats2half2_rn(A, B);   // v_cvt_pk-style pack
        wsl[i] = *(unsigned*)&h;               // 256 B/wave per instr, amp 1.0
    }
}

// ---------------- Kernel T512: ws[16][N]u32 -> out[N][32]f32, 512-pt tiles,
// b64 ws loads (requires even npts for 8-B alignment; host guards on n&1).
__global__ __launch_bounds__(256, 4) void hash4d_out512_kernel(
    const unsigned* __restrict__ ws, float* __restrict__ out, int npts)
{
    __shared__ unsigned lt[512][17];   // 34.8 KB; 4 blocks/CU fits 160 KB
    const int tid  = (int)threadIdx.x;
    const int base = (int)blockIdx.x * 512;

    if (base + 512 <= npts) {
        #pragma unroll
        for (int L = 0; L < NL; ++L) {
            // 64 lanes x 8 B contiguous = 512 B per instruction
            uint2 v = *(const uint2*)&ws[(size_t)L * npts + base + 2 * tid];
            lt[2 * tid + 0][L] = v.x;
            lt[2 * tid + 1][L] = v.y;
        }
        __syncthreads();
        const size_t ob = (size_t)base * 32;
        #pragma unroll
        for (int i = 0; i < 16; ++i) {
            int v  = i * 256 + tid;     // fvec4 index within the 512x32 tile
            int p  = v >> 3;            // local point
            int c4 = v & 7;             // 16 B chunk = level pair
            unsigned e0 = lt[p][2 * c4 + 0];
            unsigned e1 = lt[p][2 * c4 + 1];
            float2 f0 = __half22float2(*(const __half2*)&e0);
            float2 f1 = __half22float2(*(const __half2*)&e1);
            fvec4 o = { f0.x, f0.y, f1.x, f1.y };
            ((fvec4*)(out + ob))[v] = o;   // 1 KB/wave contiguous, full lines
        }
    } else {
        for (int q = tid; q < 512; q += 256) {
            int p = base + q;
            if (p < npts) {
                float* op = out + (size_t)p * 32;
                #pragma unroll
                for (int L = 0; L < NL; ++L) {
                    unsigned e = ws[(size_t)L * npts + p];
                    float2 f = __half22float2(*(const __half2*)&e);
                    op[2 * L + 0] = f.x;
                    op[2 * L + 1] = f.y;
                }
            }
        }
    }
}

// ---------------- Kernel T256 (odd-npts variant, proven in rounds 6-7)
__global__ __launch_bounds__(256, 4) void hash4d_out_kernel(
    const unsigned* __restrict__ ws, float* __restrict__ out, int npts)
{
    __shared__ unsigned lt[256][17];
    const int tid  = (int)threadIdx.x;
    const int base = (int)blockIdx.x * 256;

    if (base + 256 <= npts) {
        #pragma unroll
        for (int L = 0; L < NL; ++L) {
            lt[tid][L] = ws[(size_t)L * npts + base + tid];
        }
        __syncthreads();
        const size_t ob = (size_t)base * 32;
        #pragma unroll
        for (int i = 0; i < 8; ++i) {
            int v  = i * 256 + tid;
            int p  = v >> 3;
            int c4 = v & 7;
            unsigned e0 = lt[p][2 * c4 + 0];
            unsigned e1 = lt[p][2 * c4 + 1];
            float2 f0 = __half22float2(*(const __half2*)&e0);
            float2 f1 = __half22float2(*(const __half2*)&e1);
            fvec4 o = { f0.x, f0.y, f1.x, f1.y };
            ((fvec4*)(out + ob))[v] = o;
        }
    } else {
        int p = base + tid;
        if (p < npts) {
            float* op = out + (size_t)p * 32;
            #pragma unroll
            for (int L = 0; L < NL; ++L) {
                unsigned e = ws[(size_t)L * npts + p];
                float2 f = __half22float2(*(const __half2*)&e);
                op[2 * L + 0] = f.x;
                op[2 * L + 1] = f.y;
            }
        }
    }
}

// ---------------- Fallback (ws too small): direct global-gather kernel
__global__ __launch_bounds__(256, 4) void hash4d_kernel(
    const float* __restrict__ coords,
    const float* __restrict__ tstamps,
    const float* __restrict__ tables,
    float* __restrict__ out,
    int npts, ResArr res)
{
    int n = blockIdx.x * blockDim.x + threadIdx.x;
    if (n >= npts) return;

    float x = coords[3 * n + 0];
    float y = coords[3 * n + 1];
    float z = coords[3 * n + 2];
    float t = tstamps[n];
    t = fminf(fmaxf(t, 0.0f), 1.0f);

    float c0 = (x + 50.0f) / 100.0f;
    float c1 = (y + 50.0f) / 100.0f;
    float c2 = (z + 50.0f) / 100.0f;
    float c3 = t;

    const unsigned P1 = 2654435761u, P2 = 805459861u, P3 = 3674653429u;
    float acc[32];

    #pragma unroll
    for (int L = 0; L < NL; ++L) {
        float rf = (float)res.r[L];
        float s0 = c0 * rf, s1 = c1 * rf, s2 = c2 * rf, s3 = c3 * rf;
        float g0 = floorf(s0), g1 = floorf(s1), g2 = floorf(s2), g3 = floorf(s3);
        float f0 = s0 - g0, f1 = s1 - g1, f2 = s2 - g2, f3 = s3 - g3;

        unsigned a0 = (unsigned)(int)g0;
        unsigned a1 = (unsigned)(int)g1 * P1;
        unsigned a2 = (unsigned)(int)g2 * P2;
        unsigned a3 = (unsigned)(int)g3 * P3;
        unsigned b0 = a0 + 1u, b1 = a1 + P1, b2 = a2 + P2, b3 = a3 + P3;

        float w0a = 1.0f - f0, w0b = f0;
        float w1a = 1.0f - f1, w1b = f1;
        float w2a = 1.0f - f2, w2b = f2;
        float w3a = 1.0f - f3, w3b = f3;

        const float2* tab = ((const float2*)tables) + (size_t)L * (size_t)HS;
        float A = 0.0f, B = 0.0f;
        #pragma unroll
        for (int ci = 0; ci < 16; ++ci) {
            unsigned h = ((ci & 1) ? b0 : a0) ^ ((ci & 2) ? b1 : a1) ^
                         ((ci & 4) ? b2 : a2) ^ ((ci & 8) ? b3 : a3);
            float2 fv = tab[h & (HS - 1)];
            float w = ((((ci & 1) ? w0b : w0a) * ((ci & 2) ? w1b : w1a)) *
                       ((ci & 4) ? w2b : w2a)) * ((ci & 8) ? w3b : w3a);
            A += w * fv.x;
            B += w * fv.y;
        }
        acc[2 * L + 0] = A;
        acc[2 * L + 1] = B;
    }

    float* op = out + (size_t)n * 32;
    #pragma unroll
    for (int i = 0; i < 8; ++i) {
        fvec4 v = { acc[4 * i + 0], acc[4 * i + 1],
                    acc[4 * i + 2], acc[4 * i + 3] };
        *(fvec4*)(op + 4 * i) = v;
    }
}

extern "C" void kernel_launch(void* const* d_in, const int* in_sizes, int n_in,
                              void* d_out, int out_size, void* d_ws, size_t ws_size,
                              hipStream_t stream) {
    const float* coords  = (const float*)d_in[0];
    const float* tstamps = (const float*)d_in[1];
    const float* tables  = (const float*)d_in[2];
    float* out = (float*)d_out;

    // resolutions computed host-side with the same double-precision exp/log as the
    // reference (keeps int() truncation bit-identical; do NOT hardcode)
    ResArr ra;
    for (int l = 0; l < 16; ++l) {
        double f = (double)l / 15.0;
        double v = exp(log(16.0) * (1.0 - f) + log(512.0) * f);
        ra.r[l] = (int)v;
    }

    int n = in_sizes[0] / 3;
    size_t need = (size_t)n * NL * sizeof(unsigned);   // fp16x2 ws: 128 MB at N=2M

    // Only the ws_size guard (measured precedent) + n parity (computed ourselves).
    if (ws_size >= need) {
        hash4d_level_kernel<<<16 * WPL, TPB, 0, stream>>>(
            coords, tstamps, tables, (unsigned*)d_ws, n, ra);
        if ((n & 1) == 0) {
            hash4d_out512_kernel<<<(n + 511) / 512, 256, 0, stream>>>(
                (const unsigned*)d_ws, out, n);
        } else {
            hash4d_out_kernel<<<(n + 255) / 256, 256, 0, stream>>>(
                (const unsigned*)d_ws, out, n);
        }
    } else {
        hash4d_kernel<<<(n + 255) / 256, 256, 0, stream>>>(
            coords, tstamps, tables, out, n, ra);
    }
}